// Round 11
// baseline (347.325 us; speedup 1.0000x reference)
//
#include <hip/hip_runtime.h>
#include <hip/hip_bf16.h>

// GCN 2-layer. msg[s] = dinv[s] * (x@W)[s] stored in bf16 (dinv folded at GEMM epilogue).
// out[v] = dinv[v] * (sum_{e:dst=v} msg[src] + msg[v]) + b ; layer1 relu.
// GEMMs: MFMA 16x16x32 bf16, 2-term split (~fp32 accuracy), x tile in LDS.
// Aggregation: persistent grid-stride, one node per wave, shuffle reduce at END only.
// --- Session ledger ---
// R7: never fuse the latency-bound gather into an LDS-heavy MFMA kernel (occupancy).
// R8: nt stores only on >=64B-contiguous sectors (8B scattered nt = 4x write amp).
// R9: flat agg is TRAFFIC-bound (deeper MLP: zero delta) at ~3.8TB/s L2-miss service.
// R10: blockIdx%8->XCD pinning real (FETCH 193->46MB) but chunk-visit structures lose
//     more on execution (DS pipe / csr re-reads / divergence) than traffic saved
//     (R10 383us, R11 117us, R14 zero-delta). Flat agg1 = measured ceiling.
// R13: device-wide-atomic csr fill = 16x write amp on random 4B stores (120us).
// R16 (335us): bwcur clear folded into prep_w; BCHUNK->4096 (scatter 391 blocks).
// R17 (330.7us): build kernels 512 threads (serial passes halved). Matched.
// R18: agg2 layout fix. Old msg2 rows 144B @ 144B stride = line-misaligned ->
//     3.25 lines (208B) fetched per 144B row; R1 measured FETCH=162.7MB ✓ model.
//     Split msg2: A=[N][64] (128B rows = exactly 2 aligned lines, zero overfetch)
//     + B=[N][8] (16B rows, 1.6MB total -> L2-RESIDENT in every XCD). Predicted
//     fetch 162->~110MB. Agg2 rebuilt on the proven agg1 skeleton (8 slots x 8
//     feat-lanes, xor-shuffle over slot bits); q==0 lanes gather resident B.

#define BSH 8
#define BCHUNK 4096
#define BCAP 8192  // tmp/csr slots per bucket (mean 4096, 64-sigma slack)

typedef __attribute__((ext_vector_type(8))) short short8;
typedef __attribute__((ext_vector_type(4))) float float4v;
typedef __attribute__((ext_vector_type(2))) float float2v;

__device__ __forceinline__ float bf_lo(unsigned u) { return __uint_as_float(u << 16); }
__device__ __forceinline__ float bf_hi(unsigned u) { return __uint_as_float(u & 0xffff0000u); }
__device__ __forceinline__ float bf2f(unsigned short h) {
    return __uint_as_float((unsigned)h << 16);
}
__device__ __forceinline__ unsigned short f2bf(float f) {
    unsigned u = __float_as_uint(f);
    u += 0x7fff + ((u >> 16) & 1);  // round-to-nearest-even
    return (unsigned short)(u >> 16);
}
__device__ __forceinline__ void acc8(float* acc, uint4 m) {
    acc[0] += bf_lo(m.x); acc[1] += bf_hi(m.x);
    acc[2] += bf_lo(m.y); acc[3] += bf_hi(m.y);
    acc[4] += bf_lo(m.z); acc[5] += bf_hi(m.z);
    acc[6] += bf_lo(m.w); acc[7] += bf_hi(m.w);
}

// ---------------- CSR build (2 kernels, 512 threads, clustered writes) ----------------
__global__ __launch_bounds__(512) void k_bucket_scatter(
        const int* __restrict__ src, const int* __restrict__ dst,
        int* __restrict__ bwcur, unsigned long long* __restrict__ tmp, int E, int nb) {
    __shared__ int lh[512];
    __shared__ int lb[512];
    int t = threadIdx.x;
    for (int j = t; j < nb; j += 512) lh[j] = 0;
    __syncthreads();
    int e0 = blockIdx.x * BCHUNK;
    int e1 = min(E, e0 + BCHUNK);
    for (int e = e0 + t; e < e1; e += 512) atomicAdd(&lh[dst[e] >> BSH], 1);
    __syncthreads();
    for (int j = t; j < nb; j += 512) {
        int c = lh[j];
        lb[j] = c ? atomicAdd(&bwcur[j], c) : 0;
        lh[j] = 0;
    }
    __syncthreads();
    for (int e = e0 + t; e < e1; e += 512) {
        int d = dst[e];
        int b = d >> BSH;
        int o = atomicAdd(&lh[b], 1);
        int pos = lb[b] + o;
        if (pos < BCAP)  // memory-safe clamp
            tmp[(size_t)b * BCAP + pos] =
                ((unsigned long long)(unsigned)d << 32) | (unsigned)src[e];
    }
}

__global__ __launch_bounds__(512) void k_bucket_finalize(
        const unsigned long long* __restrict__ tmp, const int* __restrict__ bwcur,
        int* __restrict__ deg, float* __restrict__ dinv,
        int* __restrict__ rs, int* __restrict__ csr, int N) {
    __shared__ int cnt[256];
    __shared__ int sc[256];
    int b = blockIdx.x;
    int t = threadIdx.x;
    int e0 = b * BCAP;
    int e1 = e0 + min(bwcur[b], BCAP);
    if (t < 256) cnt[t] = 0;
    __syncthreads();
    for (int e = e0 + t; e < e1; e += 512) {
        int d = (int)(tmp[e] >> 32);
        atomicAdd(&cnt[d & 255], 1);
    }
    __syncthreads();
    int c = (t < 256) ? cnt[t] : 0;
    if (t < 256) sc[t] = c;
    __syncthreads();
    for (int off = 1; off < 256; off <<= 1) {
        int add = (t >= off && t < 256) ? sc[t - off] : 0;
        __syncthreads();
        if (t < 256) sc[t] += add;
        __syncthreads();
    }
    int excl = (t < 256) ? (sc[t] - c) : 0;
    __syncthreads();
    if (t < 256) sc[t] = excl;
    int node = (b << BSH) + t;
    if (t < 256 && node < N) {
        deg[node] = c;
        dinv[node] = rsqrtf((float)(c + 1));
        rs[node] = e0 + excl;
    }
    if (t < 256) cnt[t] = 0;
    __syncthreads();
    for (int e = e0 + t; e < e1; e += 512) {
        unsigned long long p = tmp[e];
        int j = ((int)(p >> 32)) & 255;
        int o = atomicAdd(&cnt[j], 1);
        csr[e0 + sc[j] + o] = (int)(p & 0xffffffffu);
    }
}

// ---------------- W pre-split (both layers) + bwcur clear, one launch ----------------
__global__ void k_prep_w(const float* __restrict__ W1, const float* __restrict__ W2,
                         unsigned short* __restrict__ w1th, unsigned short* __restrict__ w1tl,
                         unsigned short* __restrict__ w2th, unsigned short* __restrict__ w2tl,
                         int* __restrict__ bwcur) {
    if (blockIdx.x >= 104) {  // tail blocks: clear bucket cursors (nb <= 512)
        int idx = (blockIdx.x - 104) * 256 + threadIdx.x;
        if (idx < 512) bwcur[idx] = 0;
        return;
    }
    int i = blockIdx.x * blockDim.x + threadIdx.x;
    if (i < 128 * 128) {
        int col = i % 128, k = i / 128;
        float w = W1[k * 128 + col];
        unsigned short h = f2bf(w);
        w1th[(size_t)col * 128 + k] = h;
        w1tl[(size_t)col * 128 + k] = f2bf(w - bf2f(h));
    } else if (i < 128 * 128 + 80 * 128) {
        int j = i - 128 * 128;
        int col = j % 80, k = j / 80;
        float w = (col < 70) ? W2[k * 70 + col] : 0.f;
        unsigned short h = f2bf(w);
        w2th[(size_t)col * 128 + k] = h;
        w2tl[(size_t)col * 128 + k] = f2bf(w - bf2f(h));
    }
}

// ---------------- MFMA GEMM (split-bf16, ~fp32 accuracy) ----------------
// MODE 0: Y row-major [n][OSTRIDE].
// MODE 2: split64 -> col<64: Y[row*64+col]; 64<=col<72: Y[n*64 + row*8 + col-64]
//         (cols 70,71 write 0 pads); col>=72 skipped.
template <int DOUT, int OSTRIDE, int NT, int MODE>
__global__ __launch_bounds__(256, 3) void k_gemm_mfma(
        const float* __restrict__ X, const unsigned short* __restrict__ Wth,
        const unsigned short* __restrict__ Wtl,
        const float* __restrict__ dinv, unsigned short* __restrict__ Y, int n) {
    __shared__ short xs_h[64][136];
    __shared__ short xs_l[64][136];
    int t = threadIdx.x;
    int lane = t & 63, wave = t >> 6;
    int m16 = lane & 15, quad = lane >> 4;
    int r0 = blockIdx.x * 64;

    short8 bh[2][4], bl[2][4];
    int nt0 = wave, nt1 = wave + 4;
#pragma unroll
    for (int i = 0; i < 2; i++) {
        int nt = i ? nt1 : nt0;
        if (nt >= NT) continue;
        int col = nt * 16 + m16;  // < NT*16 <= padded Wt cols
#pragma unroll
        for (int kc = 0; kc < 4; kc++) {
            bh[i][kc] = *(const short8*)&Wth[(size_t)col * 128 + kc * 32 + quad * 8];
            bl[i][kc] = *(const short8*)&Wtl[(size_t)col * 128 + kc * 32 + quad * 8];
        }
    }

    for (int p = t; p < 64 * 32; p += 256) {
        int row = p >> 5;
        int k4 = p & 31;
        int gr = r0 + row;
        if (gr >= n) gr = n - 1;
        float4v xv = __builtin_nontemporal_load(
            (const float4v*)(X + (size_t)gr * 128 + 4 * k4));
        unsigned short h0 = f2bf(xv.x), h1 = f2bf(xv.y);
        unsigned short h2 = f2bf(xv.z), h3 = f2bf(xv.w);
        unsigned short l0 = f2bf(xv.x - bf2f(h0)), l1 = f2bf(xv.y - bf2f(h1));
        unsigned short l2 = f2bf(xv.z - bf2f(h2)), l3 = f2bf(xv.w - bf2f(h3));
        *(uint2*)&xs_h[row][4 * k4] =
            make_uint2((unsigned)h0 | ((unsigned)h1 << 16), (unsigned)h2 | ((unsigned)h3 << 16));
        *(uint2*)&xs_l[row][4 * k4] =
            make_uint2((unsigned)l0 | ((unsigned)l1 << 16), (unsigned)l2 | ((unsigned)l3 << 16));
    }
    __syncthreads();

    float4v acc[2][4];
#pragma unroll
    for (int i = 0; i < 2; i++)
#pragma unroll
        for (int ms = 0; ms < 4; ms++) acc[i][ms] = (float4v){0.f, 0.f, 0.f, 0.f};

#pragma unroll
    for (int kc = 0; kc < 4; kc++) {
#pragma unroll
        for (int ms = 0; ms < 4; ms++) {
            short8 ah = *(short8*)&xs_h[ms * 16 + m16][kc * 32 + quad * 8];
            short8 al = *(short8*)&xs_l[ms * 16 + m16][kc * 32 + quad * 8];
#pragma unroll
            for (int i = 0; i < 2; i++) {
                int nt = i ? nt1 : nt0;
                if (nt >= NT) continue;
                acc[i][ms] = __builtin_amdgcn_mfma_f32_16x16x32_bf16(ah, bh[i][kc], acc[i][ms], 0, 0, 0);
                acc[i][ms] = __builtin_amdgcn_mfma_f32_16x16x32_bf16(al, bh[i][kc], acc[i][ms], 0, 0, 0);
                acc[i][ms] = __builtin_amdgcn_mfma_f32_16x16x32_bf16(ah, bl[i][kc], acc[i][ms], 0, 0, 0);
            }
        }
    }

#pragma unroll
    for (int i = 0; i < 2; i++) {
        int nt = i ? nt1 : nt0;
        if (nt >= NT) continue;
        int col = nt * 16 + m16;
        if (MODE == 0 && col >= OSTRIDE) continue;
#pragma unroll
        for (int ms = 0; ms < 4; ms++) {
#pragma unroll
            for (int r = 0; r < 4; r++) {
                int row = r0 + ms * 16 + quad * 4 + r;
                if (row < n) {
                    float val = (col < DOUT) ? acc[i][ms][r] * dinv[row] : 0.f;
                    if (MODE == 0) {
                        Y[(size_t)row * OSTRIDE + col] = f2bf(val);
                    } else {
                        if (col < 64)
                            Y[(size_t)row * 64 + col] = f2bf(val);
                        else if (col < 72)
                            Y[(size_t)n * 64 + (size_t)row * 8 + (col - 64)] = f2bf(val);
                    }
                }
            }
        }
    }
}

// ---------------- agg1: persistent, one node per wave, 4 slots x 4-in-flight ----------------
__global__ __launch_bounds__(256, 8) void k_agg_w128(
        const uint4* __restrict__ msg, const float* __restrict__ dinv,
        const int* __restrict__ rs, const int* __restrict__ deg,
        const int* __restrict__ csr, const float* __restrict__ bias,
        float* __restrict__ out, int n) {
    int lane = threadIdx.x & 63;
    int q = lane & 15;
    int slot = lane >> 4;
    int wid = blockIdx.x * 4 + (threadIdx.x >> 6);
    int nw = gridDim.x * 4;
    for (int v = wid; v < n; v += nw) {
        int start = rs[v];
        int cnt = deg[v];
        float dv = dinv[v];
        uint4 mself = msg[(size_t)v * 16 + q];
        float acc[8] = {0.f, 0.f, 0.f, 0.f, 0.f, 0.f, 0.f, 0.f};
        int i = slot;
        for (; i + 12 < cnt; i += 16) {  // 4 gathers in flight per slot
            int s0 = csr[start + i];
            int s1 = csr[start + i + 4];
            int s2 = csr[start + i + 8];
            int s3 = csr[start + i + 12];
            uint4 m0 = msg[(size_t)s0 * 16 + q];
            uint4 m1 = msg[(size_t)s1 * 16 + q];
            uint4 m2 = msg[(size_t)s2 * 16 + q];
            uint4 m3 = msg[(size_t)s3 * 16 + q];
            acc8(acc, m0);
            acc8(acc, m1);
            acc8(acc, m2);
            acc8(acc, m3);
        }
        for (; i + 4 < cnt; i += 8) {  // 2 in flight
            int s0 = csr[start + i];
            int s1 = csr[start + i + 4];
            uint4 m0 = msg[(size_t)s0 * 16 + q];
            uint4 m1 = msg[(size_t)s1 * 16 + q];
            acc8(acc, m0);
            acc8(acc, m1);
        }
        if (i < cnt) {
            int s = csr[start + i];
            uint4 m = msg[(size_t)s * 16 + q];
            acc8(acc, m);
        }
#pragma unroll
        for (int j = 0; j < 8; j++) acc[j] += __shfl_xor(acc[j], 32);
#pragma unroll
        for (int j = 0; j < 8; j++) acc[j] += __shfl_xor(acc[j], 16);
        if (slot == 0) {
            float o[8];
            o[0] = acc[0] + bf_lo(mself.x); o[1] = acc[1] + bf_hi(mself.x);
            o[2] = acc[2] + bf_lo(mself.y); o[3] = acc[3] + bf_hi(mself.y);
            o[4] = acc[4] + bf_lo(mself.z); o[5] = acc[5] + bf_hi(mself.z);
            o[6] = acc[6] + bf_lo(mself.w); o[7] = acc[7] + bf_hi(mself.w);
            float r[8];
#pragma unroll
            for (int j = 0; j < 8; j++) r[j] = fmaxf(dv * o[j] + bias[8 * q + j], 0.f);
            float4v* op = (float4v*)(out + (size_t)v * 128 + 8 * q);
            __builtin_nontemporal_store((float4v){r[0], r[1], r[2], r[3]}, op);
            __builtin_nontemporal_store((float4v){r[4], r[5], r[6], r[7]}, op + 1);
        }
    }
}

// ---------------- agg2: split64 layout, agg1 skeleton (8 slots x 8 featlanes) --------
// msgA [n][8] uint4 (64 feats, 128B aligned rows); msgB [n][1] uint4 (feats 64-69 +
// 2 zero pads; 1.6MB total -> L2-resident everywhere). q==0 lanes also gather B.
__global__ __launch_bounds__(256, 8) void k_agg_w64b(
        const uint4* __restrict__ msgA, const uint4* __restrict__ msgB,
        const float* __restrict__ dinv,
        const int* __restrict__ rs, const int* __restrict__ deg,
        const int* __restrict__ csr, const float* __restrict__ bias,
        float* __restrict__ out, int n) {
    int lane = threadIdx.x & 63;
    int q = lane & 7;      // 16B feature piece 0..7
    int slot = lane >> 3;  // edge slot 0..7
    bool bq = (q == 0);
    int wid = blockIdx.x * 4 + (threadIdx.x >> 6);
    int nw = gridDim.x * 4;
    for (int v = wid; v < n; v += nw) {
        int start = rs[v];
        int cnt = deg[v];
        float dv = dinv[v];
        float acc[8] = {0.f, 0.f, 0.f, 0.f, 0.f, 0.f, 0.f, 0.f};
        float bacc[6] = {0.f, 0.f, 0.f, 0.f, 0.f, 0.f};
        int i = slot;
        for (; i + 24 < cnt; i += 32) {  // 4 gathers in flight per slot
            int s0 = csr[start + i];
            int s1 = csr[start + i + 8];
            int s2 = csr[start + i + 16];
            int s3 = csr[start + i + 24];
            uint4 a0 = msgA[(size_t)s0 * 8 + q];
            uint4 a1 = msgA[(size_t)s1 * 8 + q];
            uint4 a2 = msgA[(size_t)s2 * 8 + q];
            uint4 a3 = msgA[(size_t)s3 * 8 + q];
            acc8(acc, a0);
            acc8(acc, a1);
            acc8(acc, a2);
            acc8(acc, a3);
            if (bq) {  // L2-resident B rows
                uint4 b0 = msgB[s0];
                uint4 b1 = msgB[s1];
                uint4 b2_ = msgB[s2];
                uint4 b3 = msgB[s3];
                bacc[0] += bf_lo(b0.x) + bf_lo(b1.x) + bf_lo(b2_.x) + bf_lo(b3.x);
                bacc[1] += bf_hi(b0.x) + bf_hi(b1.x) + bf_hi(b2_.x) + bf_hi(b3.x);
                bacc[2] += bf_lo(b0.y) + bf_lo(b1.y) + bf_lo(b2_.y) + bf_lo(b3.y);
                bacc[3] += bf_hi(b0.y) + bf_hi(b1.y) + bf_hi(b2_.y) + bf_hi(b3.y);
                bacc[4] += bf_lo(b0.z) + bf_lo(b1.z) + bf_lo(b2_.z) + bf_lo(b3.z);
                bacc[5] += bf_hi(b0.z) + bf_hi(b1.z) + bf_hi(b2_.z) + bf_hi(b3.z);
            }
        }
        for (; i < cnt; i += 8) {
            int s = csr[start + i];
            uint4 a = msgA[(size_t)s * 8 + q];
            acc8(acc, a);
            if (bq) {
                uint4 b0 = msgB[s];
                bacc[0] += bf_lo(b0.x); bacc[1] += bf_hi(b0.x);
                bacc[2] += bf_lo(b0.y); bacc[3] += bf_hi(b0.y);
                bacc[4] += bf_lo(b0.z); bacc[5] += bf_hi(b0.z);
            }
        }
        // reduce across slots (lane bits 3,4,5)
#pragma unroll
        for (int j = 0; j < 8; j++) {
            acc[j] += __shfl_xor(acc[j], 8);
            acc[j] += __shfl_xor(acc[j], 16);
            acc[j] += __shfl_xor(acc[j], 32);
        }
#pragma unroll
        for (int j = 0; j < 6; j++) {
            bacc[j] += __shfl_xor(bacc[j], 8);
            bacc[j] += __shfl_xor(bacc[j], 16);
            bacc[j] += __shfl_xor(bacc[j], 32);
        }
        if (slot == 0) {
            uint4 aself = msgA[(size_t)v * 8 + q];
            float o[8];
            o[0] = acc[0] + bf_lo(aself.x); o[1] = acc[1] + bf_hi(aself.x);
            o[2] = acc[2] + bf_lo(aself.y); o[3] = acc[3] + bf_hi(aself.y);
            o[4] = acc[4] + bf_lo(aself.z); o[5] = acc[5] + bf_hi(aself.z);
            o[6] = acc[6] + bf_lo(aself.w); o[7] = acc[7] + bf_hi(aself.w);
            float* orow = out + (size_t)v * 70 + 8 * q;
#pragma unroll
            for (int jj = 0; jj < 4; jj++) {
                float2 st = make_float2(dv * o[2 * jj] + bias[8 * q + 2 * jj],
                                        dv * o[2 * jj + 1] + bias[8 * q + 2 * jj + 1]);
                *(float2*)(orow + 2 * jj) = st;  // cached (R8: 280B rows unaligned)
            }
            if (q == 0) {  // features 64..69 from B
                uint4 bself = msgB[v];
                float bo[6];
                bo[0] = bacc[0] + bf_lo(bself.x); bo[1] = bacc[1] + bf_hi(bself.x);
                bo[2] = bacc[2] + bf_lo(bself.y); bo[3] = bacc[3] + bf_hi(bself.y);
                bo[4] = bacc[4] + bf_lo(bself.z); bo[5] = bacc[5] + bf_hi(bself.z);
                float* brow = out + (size_t)v * 70 + 64;
#pragma unroll
                for (int jj = 0; jj < 3; jj++) {
                    float2 st = make_float2(dv * bo[2 * jj] + bias[64 + 2 * jj],
                                            dv * bo[2 * jj + 1] + bias[64 + 2 * jj + 1]);
                    *(float2*)(brow + 2 * jj) = st;
                }
            }
        }
    }
}

static inline size_t alignup(size_t x) { return (x + 255) & ~(size_t)255; }

extern "C" void kernel_launch(void* const* d_in, const int* in_sizes, int n_in,
                              void* d_out, int out_size, void* d_ws, size_t ws_size,
                              hipStream_t stream) {
    const float* x = (const float*)d_in[0];
    const int* edge = (const int*)d_in[1];
    const float* W1 = (const float*)d_in[2];
    const float* b1 = (const float*)d_in[3];
    const float* W2 = (const float*)d_in[4];
    const float* b2 = (const float*)d_in[5];

    const int N = in_sizes[0] / 128;
    const int E = in_sizes[1] / 2;
    const int* src = edge;
    const int* dst = edge + E;
    const int nb = (N + 255) >> BSH;

    char* w = (char*)d_ws;
    int* deg = (int*)w;              w += alignup((size_t)N * 4);
    float* dinv = (float*)w;         w += alignup((size_t)N * 4);
    int* rs = (int*)w;               w += alignup((size_t)N * 4);
    int* bwcur = (int*)w;            w += alignup(4096);
    int* csr = (int*)w;              w += alignup((size_t)nb * BCAP * 4);
    unsigned short* msg1 = (unsigned short*)w; w += alignup((size_t)N * 128 * 2);
    unsigned short* msg2 = (unsigned short*)w; w += alignup((size_t)N * 72 * 2);  // A[N][64] + B[N][8]
    unsigned short* w1th = (unsigned short*)w; w += alignup(128 * 128 * 2);
    unsigned short* w1tl = (unsigned short*)w; w += alignup(128 * 128 * 2);
    unsigned short* w2th = (unsigned short*)w; w += alignup(80 * 128 * 2);
    unsigned short* w2tl = (unsigned short*)w; w += alignup(80 * 128 * 2);
    float* h = (float*)w;            w += alignup((size_t)N * 128 * 4);
    unsigned long long* tmp = (unsigned long long*)h;  // aliases h (disjoint in time)

    // ---- W pre-split + bwcur clear (one launch; precedes scatter on-stream) ----
    k_prep_w<<<104 + 2, 256, 0, stream>>>(W1, W2, w1th, w1tl, w2th, w2tl, bwcur);

    // ---- CSR build: direct bucketed scatter with CAP slack, 512-thread blocks ----
    k_bucket_scatter<<<(E + BCHUNK - 1) / BCHUNK, 512, 0, stream>>>(src, dst, bwcur, tmp, E, nb);
    k_bucket_finalize<<<nb, 512, 0, stream>>>(tmp, bwcur, deg, dinv, rs, csr, N);

    int gblocks = (N + 63) / 64;

    // Layer 1: msg1 = bf16(dinv * (x @ W1)) [N,128] ; agg -> h [N,128] fp32 (bias+relu)
    k_gemm_mfma<128, 128, 8, 0><<<gblocks, 256, 0, stream>>>(x, w1th, w1tl, dinv, msg1, N);
    k_agg_w128<<<2048, 256, 0, stream>>>((const uint4*)msg1, dinv, rs, deg, csr, b1, h, N);

    // Layer 2: msg2 split64 A[N][64]+B[N][8] ; agg -> d_out [N,70] (bias)
    k_gemm_mfma<70, 72, 5, 2><<<gblocks, 256, 0, stream>>>(h, w2th, w2tl, dinv, msg2, N);
    k_agg_w64b<<<2048, 256, 0, stream>>>(
        (const uint4*)msg2, (const uint4*)(msg2 + (size_t)N * 64), dinv, rs, deg, csr,
        b2, (float*)d_out, N);
}

// Round 12
// 327.593 us; speedup vs baseline: 1.0602x; 1.0602x over previous
//
#include <hip/hip_runtime.h>
#include <hip/hip_bf16.h>

// GCN 2-layer. msg[s] = dinv[s] * (x@W)[s] stored in bf16 (dinv folded at GEMM epilogue).
// out[v] = dinv[v] * (sum_{e:dst=v} msg[src] + msg[v]) + b ; layer1 relu.
// GEMMs: MFMA 16x16x32 bf16, 2-term split (~fp32 accuracy), x tile in LDS.
// Aggregation: persistent grid-stride, one node per wave, shuffle reduce at END only.
// --- Session ledger (final) ---
// R7: never fuse the latency-bound gather into an LDS-heavy MFMA kernel (occupancy).
// R8: nt stores only on >=64B-contiguous sectors (8B scattered nt = 4x write amp).
// R9: flat agg is TRAFFIC-bound (deeper MLP: zero delta) at ~3.8TB/s L2-miss service.
// R10: blockIdx%8->XCD pinning real (FETCH 193->46MB) but chunk-visit structures lose
//     more on execution (DS pipe / csr re-reads / divergence) than traffic saved.
// R11/R13/R14: per-lane serial walk, atomic fill, half-split - all dominated.
// R18: agg2 split64 layout: fetch barely moved (158 vs 162MB - at ~86% row coverage
//     neighboring rows share lines, so alignment overfetch is ~nil; traffic = 8x array
//     + csr + out-RFO) and the 8-lane piecewise store pattern cost +43MB write amp.
//     Agg2's 9-lane w72 form is its floor. REVERTED.
// Final config (R17, 330.7us): flat aggs at measured ceilings (agg1: 65us, 192.7MB,
//     3.8TB/s bit-stable across 6 runs) + 512-thread bucketed CSR build + fused
//     prep_w/bwcur-clear + float4 nt gemm staging.

#define BSH 8
#define BCHUNK 4096
#define BCAP 8192  // tmp/csr slots per bucket (mean 4096, 64-sigma slack)

typedef __attribute__((ext_vector_type(8))) short short8;
typedef __attribute__((ext_vector_type(4))) float float4v;
typedef __attribute__((ext_vector_type(2))) float float2v;

__device__ __forceinline__ float bf_lo(unsigned u) { return __uint_as_float(u << 16); }
__device__ __forceinline__ float bf_hi(unsigned u) { return __uint_as_float(u & 0xffff0000u); }
__device__ __forceinline__ float bf2f(unsigned short h) {
    return __uint_as_float((unsigned)h << 16);
}
__device__ __forceinline__ unsigned short f2bf(float f) {
    unsigned u = __float_as_uint(f);
    u += 0x7fff + ((u >> 16) & 1);  // round-to-nearest-even
    return (unsigned short)(u >> 16);
}
__device__ __forceinline__ void acc8(float* acc, uint4 m) {
    acc[0] += bf_lo(m.x); acc[1] += bf_hi(m.x);
    acc[2] += bf_lo(m.y); acc[3] += bf_hi(m.y);
    acc[4] += bf_lo(m.z); acc[5] += bf_hi(m.z);
    acc[6] += bf_lo(m.w); acc[7] += bf_hi(m.w);
}

// ---------------- CSR build (2 kernels, 512 threads, clustered writes) ----------------
__global__ __launch_bounds__(512) void k_bucket_scatter(
        const int* __restrict__ src, const int* __restrict__ dst,
        int* __restrict__ bwcur, unsigned long long* __restrict__ tmp, int E, int nb) {
    __shared__ int lh[512];
    __shared__ int lb[512];
    int t = threadIdx.x;
    for (int j = t; j < nb; j += 512) lh[j] = 0;
    __syncthreads();
    int e0 = blockIdx.x * BCHUNK;
    int e1 = min(E, e0 + BCHUNK);
    for (int e = e0 + t; e < e1; e += 512) atomicAdd(&lh[dst[e] >> BSH], 1);
    __syncthreads();
    for (int j = t; j < nb; j += 512) {
        int c = lh[j];
        lb[j] = c ? atomicAdd(&bwcur[j], c) : 0;
        lh[j] = 0;
    }
    __syncthreads();
    for (int e = e0 + t; e < e1; e += 512) {
        int d = dst[e];
        int b = d >> BSH;
        int o = atomicAdd(&lh[b], 1);
        int pos = lb[b] + o;
        if (pos < BCAP)  // memory-safe clamp
            tmp[(size_t)b * BCAP + pos] =
                ((unsigned long long)(unsigned)d << 32) | (unsigned)src[e];
    }
}

__global__ __launch_bounds__(512) void k_bucket_finalize(
        const unsigned long long* __restrict__ tmp, const int* __restrict__ bwcur,
        int* __restrict__ deg, float* __restrict__ dinv,
        int* __restrict__ rs, int* __restrict__ csr, int N) {
    __shared__ int cnt[256];
    __shared__ int sc[256];
    int b = blockIdx.x;
    int t = threadIdx.x;
    int e0 = b * BCAP;
    int e1 = e0 + min(bwcur[b], BCAP);
    if (t < 256) cnt[t] = 0;
    __syncthreads();
    for (int e = e0 + t; e < e1; e += 512) {
        int d = (int)(tmp[e] >> 32);
        atomicAdd(&cnt[d & 255], 1);
    }
    __syncthreads();
    int c = (t < 256) ? cnt[t] : 0;
    if (t < 256) sc[t] = c;
    __syncthreads();
    for (int off = 1; off < 256; off <<= 1) {
        int add = (t >= off && t < 256) ? sc[t - off] : 0;
        __syncthreads();
        if (t < 256) sc[t] += add;
        __syncthreads();
    }
    int excl = (t < 256) ? (sc[t] - c) : 0;
    __syncthreads();
    if (t < 256) sc[t] = excl;
    int node = (b << BSH) + t;
    if (t < 256 && node < N) {
        deg[node] = c;
        dinv[node] = rsqrtf((float)(c + 1));
        rs[node] = e0 + excl;
    }
    if (t < 256) cnt[t] = 0;
    __syncthreads();
    for (int e = e0 + t; e < e1; e += 512) {
        unsigned long long p = tmp[e];
        int j = ((int)(p >> 32)) & 255;
        int o = atomicAdd(&cnt[j], 1);
        csr[e0 + sc[j] + o] = (int)(p & 0xffffffffu);
    }
}

// ---------------- W pre-split (both layers) + bwcur clear, one launch ----------------
__global__ void k_prep_w(const float* __restrict__ W1, const float* __restrict__ W2,
                         unsigned short* __restrict__ w1th, unsigned short* __restrict__ w1tl,
                         unsigned short* __restrict__ w2th, unsigned short* __restrict__ w2tl,
                         int* __restrict__ bwcur) {
    if (blockIdx.x >= 104) {  // tail blocks: clear bucket cursors (nb <= 512)
        int idx = (blockIdx.x - 104) * 256 + threadIdx.x;
        if (idx < 512) bwcur[idx] = 0;
        return;
    }
    int i = blockIdx.x * blockDim.x + threadIdx.x;
    if (i < 128 * 128) {
        int col = i % 128, k = i / 128;
        float w = W1[k * 128 + col];
        unsigned short h = f2bf(w);
        w1th[(size_t)col * 128 + k] = h;
        w1tl[(size_t)col * 128 + k] = f2bf(w - bf2f(h));
    } else if (i < 128 * 128 + 80 * 128) {
        int j = i - 128 * 128;
        int col = j % 80, k = j / 80;
        float w = (col < 70) ? W2[k * 70 + col] : 0.f;
        unsigned short h = f2bf(w);
        w2th[(size_t)col * 128 + k] = h;
        w2tl[(size_t)col * 128 + k] = f2bf(w - bf2f(h));
    }
}

// ---------------- MFMA GEMM (split-bf16, ~fp32 accuracy) ----------------
// Y[r,c] = bf16(dinv[r] * (X@W)[r,c]). Block: 4 waves, 64 rows, K=128.
// B frags loaded as 16B vectors from pre-split Wt. X staged via float4 nt loads.
template <int DOUT, int OSTRIDE, int NT>
__global__ __launch_bounds__(256, 3) void k_gemm_mfma(
        const float* __restrict__ X, const unsigned short* __restrict__ Wth,
        const unsigned short* __restrict__ Wtl,
        const float* __restrict__ dinv, unsigned short* __restrict__ Y, int n) {
    __shared__ short xs_h[64][136];
    __shared__ short xs_l[64][136];
    int t = threadIdx.x;
    int lane = t & 63, wave = t >> 6;
    int m16 = lane & 15, quad = lane >> 4;
    int r0 = blockIdx.x * 64;

    short8 bh[2][4], bl[2][4];
    int nt0 = wave, nt1 = wave + 4;
#pragma unroll
    for (int i = 0; i < 2; i++) {
        int nt = i ? nt1 : nt0;
        if (nt >= NT) continue;
        int col = nt * 16 + m16;  // < NT*16 <= padded Wt cols
#pragma unroll
        for (int kc = 0; kc < 4; kc++) {
            bh[i][kc] = *(const short8*)&Wth[(size_t)col * 128 + kc * 32 + quad * 8];
            bl[i][kc] = *(const short8*)&Wtl[(size_t)col * 128 + kc * 32 + quad * 8];
        }
    }

    for (int p = t; p < 64 * 32; p += 256) {
        int row = p >> 5;
        int k4 = p & 31;
        int gr = r0 + row;
        if (gr >= n) gr = n - 1;
        float4v xv = __builtin_nontemporal_load(
            (const float4v*)(X + (size_t)gr * 128 + 4 * k4));
        unsigned short h0 = f2bf(xv.x), h1 = f2bf(xv.y);
        unsigned short h2 = f2bf(xv.z), h3 = f2bf(xv.w);
        unsigned short l0 = f2bf(xv.x - bf2f(h0)), l1 = f2bf(xv.y - bf2f(h1));
        unsigned short l2 = f2bf(xv.z - bf2f(h2)), l3 = f2bf(xv.w - bf2f(h3));
        *(uint2*)&xs_h[row][4 * k4] =
            make_uint2((unsigned)h0 | ((unsigned)h1 << 16), (unsigned)h2 | ((unsigned)h3 << 16));
        *(uint2*)&xs_l[row][4 * k4] =
            make_uint2((unsigned)l0 | ((unsigned)l1 << 16), (unsigned)l2 | ((unsigned)l3 << 16));
    }
    __syncthreads();

    float4v acc[2][4];
#pragma unroll
    for (int i = 0; i < 2; i++)
#pragma unroll
        for (int ms = 0; ms < 4; ms++) acc[i][ms] = (float4v){0.f, 0.f, 0.f, 0.f};

#pragma unroll
    for (int kc = 0; kc < 4; kc++) {
#pragma unroll
        for (int ms = 0; ms < 4; ms++) {
            short8 ah = *(short8*)&xs_h[ms * 16 + m16][kc * 32 + quad * 8];
            short8 al = *(short8*)&xs_l[ms * 16 + m16][kc * 32 + quad * 8];
#pragma unroll
            for (int i = 0; i < 2; i++) {
                int nt = i ? nt1 : nt0;
                if (nt >= NT) continue;
                acc[i][ms] = __builtin_amdgcn_mfma_f32_16x16x32_bf16(ah, bh[i][kc], acc[i][ms], 0, 0, 0);
                acc[i][ms] = __builtin_amdgcn_mfma_f32_16x16x32_bf16(al, bh[i][kc], acc[i][ms], 0, 0, 0);
                acc[i][ms] = __builtin_amdgcn_mfma_f32_16x16x32_bf16(ah, bl[i][kc], acc[i][ms], 0, 0, 0);
            }
        }
    }

#pragma unroll
    for (int i = 0; i < 2; i++) {
        int nt = i ? nt1 : nt0;
        if (nt >= NT) continue;
        int col = nt * 16 + m16;
        if (col >= OSTRIDE) continue;
#pragma unroll
        for (int ms = 0; ms < 4; ms++) {
#pragma unroll
            for (int r = 0; r < 4; r++) {
                int row = r0 + ms * 16 + quad * 4 + r;
                if (row < n) {
                    float val = (col < DOUT) ? acc[i][ms][r] * dinv[row] : 0.f;
                    Y[(size_t)row * OSTRIDE + col] = f2bf(val);
                }
            }
        }
    }
}

// ---------------- agg1: persistent, one node per wave, 4 slots x 4-in-flight ----------------
__global__ __launch_bounds__(256, 8) void k_agg_w128(
        const uint4* __restrict__ msg, const float* __restrict__ dinv,
        const int* __restrict__ rs, const int* __restrict__ deg,
        const int* __restrict__ csr, const float* __restrict__ bias,
        float* __restrict__ out, int n) {
    int lane = threadIdx.x & 63;
    int q = lane & 15;
    int slot = lane >> 4;
    int wid = blockIdx.x * 4 + (threadIdx.x >> 6);
    int nw = gridDim.x * 4;
    for (int v = wid; v < n; v += nw) {
        int start = rs[v];
        int cnt = deg[v];
        float dv = dinv[v];
        uint4 mself = msg[(size_t)v * 16 + q];
        float acc[8] = {0.f, 0.f, 0.f, 0.f, 0.f, 0.f, 0.f, 0.f};
        int i = slot;
        for (; i + 12 < cnt; i += 16) {  // 4 gathers in flight per slot
            int s0 = csr[start + i];
            int s1 = csr[start + i + 4];
            int s2 = csr[start + i + 8];
            int s3 = csr[start + i + 12];
            uint4 m0 = msg[(size_t)s0 * 16 + q];
            uint4 m1 = msg[(size_t)s1 * 16 + q];
            uint4 m2 = msg[(size_t)s2 * 16 + q];
            uint4 m3 = msg[(size_t)s3 * 16 + q];
            acc8(acc, m0);
            acc8(acc, m1);
            acc8(acc, m2);
            acc8(acc, m3);
        }
        for (; i + 4 < cnt; i += 8) {  // 2 in flight
            int s0 = csr[start + i];
            int s1 = csr[start + i + 4];
            uint4 m0 = msg[(size_t)s0 * 16 + q];
            uint4 m1 = msg[(size_t)s1 * 16 + q];
            acc8(acc, m0);
            acc8(acc, m1);
        }
        if (i < cnt) {
            int s = csr[start + i];
            uint4 m = msg[(size_t)s * 16 + q];
            acc8(acc, m);
        }
#pragma unroll
        for (int j = 0; j < 8; j++) acc[j] += __shfl_xor(acc[j], 32);
#pragma unroll
        for (int j = 0; j < 8; j++) acc[j] += __shfl_xor(acc[j], 16);
        if (slot == 0) {
            float o[8];
            o[0] = acc[0] + bf_lo(mself.x); o[1] = acc[1] + bf_hi(mself.x);
            o[2] = acc[2] + bf_lo(mself.y); o[3] = acc[3] + bf_hi(mself.y);
            o[4] = acc[4] + bf_lo(mself.z); o[5] = acc[5] + bf_hi(mself.z);
            o[6] = acc[6] + bf_lo(mself.w); o[7] = acc[7] + bf_hi(mself.w);
            float r[8];
#pragma unroll
            for (int j = 0; j < 8; j++) r[j] = fmaxf(dv * o[j] + bias[8 * q + j], 0.f);
            float4v* op = (float4v*)(out + (size_t)v * 128 + 8 * q);
            __builtin_nontemporal_store((float4v){r[0], r[1], r[2], r[3]}, op);
            __builtin_nontemporal_store((float4v){r[4], r[5], r[6], r[7]}, op + 1);
        }
    }
}

// ---------------- agg2: persistent, one node per wave, 7 slots x 9 lanes, 3-in-flight ----------------
__global__ __launch_bounds__(256, 8) void k_agg_w72(
        const uint4* __restrict__ msg, const float* __restrict__ dinv,
        const int* __restrict__ rs, const int* __restrict__ deg,
        const int* __restrict__ csr, const float* __restrict__ bias,
        float* __restrict__ out, int n) {
    int lane = threadIdx.x & 63;
    int slot = lane / 9;
    int q = lane - slot * 9;
    bool active = lane < 63;
    int wid = blockIdx.x * 4 + (threadIdx.x >> 6);
    int nw = gridDim.x * 4;
    for (int v = wid; v < n; v += nw) {
        int start = rs[v];
        int cnt = deg[v];
        float dv = dinv[v];
        float acc[8] = {0.f, 0.f, 0.f, 0.f, 0.f, 0.f, 0.f, 0.f};
        uint4 mself = make_uint4(0, 0, 0, 0);
        if (active) {
            mself = msg[(size_t)v * 9 + q];
            int i = slot;
            for (; i + 14 < cnt; i += 21) {  // 3 gathers in flight per slot
                int s0 = csr[start + i];
                int s1 = csr[start + i + 7];
                int s2 = csr[start + i + 14];
                uint4 m0 = msg[(size_t)s0 * 9 + q];
                uint4 m1 = msg[(size_t)s1 * 9 + q];
                uint4 m2 = msg[(size_t)s2 * 9 + q];
                acc8(acc, m0);
                acc8(acc, m1);
                acc8(acc, m2);
            }
            for (; i + 7 < cnt; i += 14) {
                int s0 = csr[start + i];
                int s1 = csr[start + i + 7];
                uint4 m0 = msg[(size_t)s0 * 9 + q];
                uint4 m1 = msg[(size_t)s1 * 9 + q];
                acc8(acc, m0);
                acc8(acc, m1);
            }
            if (i < cnt) {
                int s = csr[start + i];
                uint4 m = msg[(size_t)s * 9 + q];
                acc8(acc, m);
            }
        }
#pragma unroll
        for (int j = 0; j < 8; j++) {
            float t27 = __shfl(acc[j], lane + 27);
            if (lane < 27) acc[j] += t27;
        }
#pragma unroll
        for (int j = 0; j < 8; j++) {
            float t54 = __shfl(acc[j], lane + 54);
            float t9  = __shfl(acc[j], lane + 9);
            float t18 = __shfl(acc[j], lane + 18);
            if (lane < 9) acc[j] += t54 + t9 + t18;
        }
        if (lane < 9) {
            float o[8];
            o[0] = acc[0] + bf_lo(mself.x); o[1] = acc[1] + bf_hi(mself.x);
            o[2] = acc[2] + bf_lo(mself.y); o[3] = acc[3] + bf_hi(mself.y);
            o[4] = acc[4] + bf_lo(mself.z); o[5] = acc[5] + bf_hi(mself.z);
            o[6] = acc[6] + bf_lo(mself.w); o[7] = acc[7] + bf_hi(mself.w);
            float* orow = out + (size_t)v * 70 + 8 * q;
#pragma unroll
            for (int jj = 0; jj < 4; jj++) {
                int f = 8 * q + 2 * jj;
                if (f < 70) {
                    float2 st = make_float2(dv * o[2 * jj] + bias[f],
                                            dv * o[2 * jj + 1] + bias[f + 1]);
                    *(float2*)(orow + 2 * jj) = st;  // cached: L2 coalesces partial lines
                }
            }
        }
    }
}

static inline size_t alignup(size_t x) { return (x + 255) & ~(size_t)255; }

extern "C" void kernel_launch(void* const* d_in, const int* in_sizes, int n_in,
                              void* d_out, int out_size, void* d_ws, size_t ws_size,
                              hipStream_t stream) {
    const float* x = (const float*)d_in[0];
    const int* edge = (const int*)d_in[1];
    const float* W1 = (const float*)d_in[2];
    const float* b1 = (const float*)d_in[3];
    const float* W2 = (const float*)d_in[4];
    const float* b2 = (const float*)d_in[5];

    const int N = in_sizes[0] / 128;
    const int E = in_sizes[1] / 2;
    const int* src = edge;
    const int* dst = edge + E;
    const int nb = (N + 255) >> BSH;

    char* w = (char*)d_ws;
    int* deg = (int*)w;              w += alignup((size_t)N * 4);
    float* dinv = (float*)w;         w += alignup((size_t)N * 4);
    int* rs = (int*)w;               w += alignup((size_t)N * 4);
    int* bwcur = (int*)w;            w += alignup(4096);
    int* csr = (int*)w;              w += alignup((size_t)nb * BCAP * 4);
    unsigned short* msg1 = (unsigned short*)w; w += alignup((size_t)N * 128 * 2);
    unsigned short* msg2 = (unsigned short*)w; w += alignup((size_t)N * 72 * 2);
    unsigned short* w1th = (unsigned short*)w; w += alignup(128 * 128 * 2);
    unsigned short* w1tl = (unsigned short*)w; w += alignup(128 * 128 * 2);
    unsigned short* w2th = (unsigned short*)w; w += alignup(80 * 128 * 2);
    unsigned short* w2tl = (unsigned short*)w; w += alignup(80 * 128 * 2);
    float* h = (float*)w;            w += alignup((size_t)N * 128 * 4);
    unsigned long long* tmp = (unsigned long long*)h;  // aliases h (disjoint in time)

    // ---- W pre-split + bwcur clear (one launch; precedes scatter on-stream) ----
    k_prep_w<<<104 + 2, 256, 0, stream>>>(W1, W2, w1th, w1tl, w2th, w2tl, bwcur);

    // ---- CSR build: direct bucketed scatter with CAP slack, 512-thread blocks ----
    k_bucket_scatter<<<(E + BCHUNK - 1) / BCHUNK, 512, 0, stream>>>(src, dst, bwcur, tmp, E, nb);
    k_bucket_finalize<<<nb, 512, 0, stream>>>(tmp, bwcur, deg, dinv, rs, csr, N);

    int gblocks = (N + 63) / 64;

    // Layer 1: msg1 = bf16(dinv * (x @ W1)) [N,128] ; agg -> h [N,128] fp32 (bias+relu)
    k_gemm_mfma<128, 128, 8><<<gblocks, 256, 0, stream>>>(x, w1th, w1tl, dinv, msg1, N);
    k_agg_w128<<<2048, 256, 0, stream>>>((const uint4*)msg1, dinv, rs, deg, csr, b1, h, N);

    // Layer 2: msg2 = bf16(dinv * (h @ W2)) [N,72 pad] ; agg -> d_out [N,70] (bias)
    k_gemm_mfma<70, 72, 5><<<gblocks, 256, 0, stream>>>(h, w2th, w2tl, dinv, msg2, N);
    k_agg_w72<<<2048, 256, 0, stream>>>((const uint4*)msg2, dinv, rs, deg, csr, b2,
                                        (float*)d_out, N);
}